// Round 4
// baseline (574.632 us; speedup 1.0000x reference)
//
#include <hip/hip_runtime.h>
#include <hip/hip_bf16.h>

// GraphSage: 3x SAGEConv(mean) + linear head.
// Precision scheme: all feature matrices stored as packed split-bf16
// (uint32 = hi<<16 | lo, value = f(hi)+f(lo), rel err ~2^-17 ~ fp32-ish).
// GEMM runs on MFMA bf16 16x16x32 with 3 products per K-chunk:
//   A_hi*B_hi + A_lo*B_hi + A_hi*B_lo  (fp32 AGPR accumulate)
// -> matrix pipe instead of fp32 VALU; no LDS, no barriers in the GEMM.
// CSR build once per call (edge_index is int32: [src[0..E), dst[0..E)]).

constexpr int NN = 50000;
constexpr int NE = 800000;
constexpr int NCH = (NN + 255) / 256;

using bf16x8 = __attribute__((ext_vector_type(8))) short;
using f32x4  = __attribute__((ext_vector_type(4))) float;

__device__ __forceinline__ unsigned short bf16_rne(float f) {
    unsigned u = __float_as_uint(f);
    unsigned r = (u + 0x7FFFu + ((u >> 16) & 1u)) >> 16;
    return (unsigned short)r;
}
__device__ __forceinline__ float bf16_f(unsigned short h) {
    return __uint_as_float(((unsigned)h) << 16);
}
__device__ __forceinline__ unsigned pack_split(float v) {
    unsigned short hi = bf16_rne(v);
    float r = v - bf16_f(hi);
    unsigned short lo = bf16_rne(r);
    return (((unsigned)hi) << 16) | (unsigned)lo;
}
__device__ __forceinline__ float unpack_f(unsigned p) {
    return bf16_f((unsigned short)(p >> 16)) + bf16_f((unsigned short)(p & 0xFFFFu));
}

// ---------------- CSR build ----------------

__global__ void k_zero_int(int* __restrict__ a, int n) {
    int i = blockIdx.x * blockDim.x + threadIdx.x;
    if (i < n) a[i] = 0;
}

__global__ void k_count(const int* __restrict__ ei, int* __restrict__ cnt) {
    int e = blockIdx.x * blockDim.x + threadIdx.x;
    if (e < NE) atomicAdd(&cnt[ei[NE + e]], 1);
}

__global__ void k_chunk_sums(const int* __restrict__ cnt, int* __restrict__ partial) {
    __shared__ int ws[4];
    int i = blockIdx.x * 256 + threadIdx.x;
    int v = (i < NN) ? cnt[i] : 0;
    for (int o = 32; o > 0; o >>= 1) v += __shfl_down(v, o);
    int lane = threadIdx.x & 63, wave = threadIdx.x >> 6;
    if (lane == 0) ws[wave] = v;
    __syncthreads();
    if (threadIdx.x == 0) partial[blockIdx.x] = ws[0] + ws[1] + ws[2] + ws[3];
}

__global__ void k_scan_partials(int* __restrict__ partial, int n) {
    __shared__ int ws[4];
    int t = threadIdx.x;
    int orig = (t < n) ? partial[t] : 0;
    int v = orig;
    int lane = t & 63, wave = t >> 6;
    for (int o = 1; o < 64; o <<= 1) { int u = __shfl_up(v, o); if (lane >= o) v += u; }
    if (lane == 63) ws[wave] = v;
    __syncthreads();
    int off = 0;
    for (int w = 0; w < 4; ++w) if (w < wave) off += ws[w];
    if (t < n) partial[t] = v + off - orig;
}

__global__ void k_scan_chunks(const int* __restrict__ cnt, const int* __restrict__ partial,
                              int* __restrict__ cursor) {
    __shared__ int ws[4];
    int i = blockIdx.x * 256 + threadIdx.x;
    int orig = (i < NN) ? cnt[i] : 0;
    int v = orig;
    int lane = threadIdx.x & 63, wave = threadIdx.x >> 6;
    for (int o = 1; o < 64; o <<= 1) { int u = __shfl_up(v, o); if (lane >= o) v += u; }
    if (lane == 63) ws[wave] = v;
    __syncthreads();
    int off = partial[blockIdx.x];
    for (int w = 0; w < 4; ++w) if (w < wave) off += ws[w];
    if (i < NN) cursor[i] = v - orig + off;
}

__global__ void k_scatter(const int* __restrict__ ei, int* __restrict__ cursor,
                          int* __restrict__ perm) {
    int e = blockIdx.x * blockDim.x + threadIdx.x;
    if (e < NE) {
        int s = ei[e];
        int d = ei[NE + e];
        int pos = atomicAdd(&cursor[d], 1);
        perm[pos] = s;
    }
}

// ---------------- packing ----------------

// x fp32 [N*128] -> packed split-bf16
__global__ void k_pack_x(const float* __restrict__ x, unsigned* __restrict__ xp) {
    int i = blockIdx.x * blockDim.x + threadIdx.x;
    constexpr int TOT = NN * 128 / 4;
    if (i < TOT) {
        float4 v = ((const float4*)x)[i];
        uint4 o;
        o.x = pack_split(v.x); o.y = pack_split(v.y);
        o.z = pack_split(v.z); o.w = pack_split(v.w);
        ((uint4*)xp)[i] = o;
    }
}

// weights: Wl,Wr [128 out][128 in] fp32 -> combined hi/lo bf16 planes [128][256]
// (k<128 from Wl, k>=128 from Wr)
__global__ void k_pack_w(const float* __restrict__ Wl, const float* __restrict__ Wr,
                         unsigned short* __restrict__ whi, unsigned short* __restrict__ wlo) {
    int i = blockIdx.x * blockDim.x + threadIdx.x;   // 128*256
    if (i < 128 * 256) {
        int c = i >> 8;
        int k = i & 255;
        float v = (k < 128) ? Wl[c * 128 + k] : Wr[c * 128 + (k - 128)];
        unsigned short hi = bf16_rne(v);
        whi[i] = hi;
        wlo[i] = bf16_rne(v - bf16_f(hi));
    }
}

// ---------------- aggregate (mean over CSR neighbors) ----------------
// one wave per node; lane l holds cols [2l, 2l+1] (packed uint2)
__global__ __launch_bounds__(256) void k_aggregate(const unsigned* __restrict__ hp,
        const int* __restrict__ cursor, const int* __restrict__ cnt,
        const int* __restrict__ perm, unsigned* __restrict__ outp) {
    int wave = __builtin_amdgcn_readfirstlane(threadIdx.x >> 6);
    int lane = threadIdx.x & 63;
    int node = blockIdx.x * 4 + wave;
    if (node >= NN) return;
    int deg = cnt[node];
    int start = cursor[node] - deg;
    float ax = 0.f, ay = 0.f;
    int j = 0;
    for (; j + 4 <= deg; j += 4) {
        int s0 = perm[start + j + 0];
        int s1 = perm[start + j + 1];
        int s2 = perm[start + j + 2];
        int s3 = perm[start + j + 3];
        uint2 q0 = ((const uint2*)(hp + (size_t)s0 * 128))[lane];
        uint2 q1 = ((const uint2*)(hp + (size_t)s1 * 128))[lane];
        uint2 q2 = ((const uint2*)(hp + (size_t)s2 * 128))[lane];
        uint2 q3 = ((const uint2*)(hp + (size_t)s3 * 128))[lane];
        ax += (unpack_f(q0.x) + unpack_f(q1.x)) + (unpack_f(q2.x) + unpack_f(q3.x));
        ay += (unpack_f(q0.y) + unpack_f(q1.y)) + (unpack_f(q2.y) + unpack_f(q3.y));
    }
    for (; j < deg; ++j) {
        int s = perm[start + j];
        uint2 q = ((const uint2*)(hp + (size_t)s * 128))[lane];
        ax += unpack_f(q.x);
        ay += unpack_f(q.y);
    }
    float inv = 1.0f / (float)(deg > 1 ? deg : 1);
    uint2 o;
    o.x = pack_split(ax * inv);
    o.y = pack_split(ay * inv);
    ((uint2*)(outp + (size_t)node * 128))[lane] = o;
}

// ---------------- MFMA GEMM ----------------
// out[n][c] = relu( bias[c] + sum_{k<128} A0[n][k] Wl[c][k] + sum A1[n][k] Wr[c][k] )
// A0,A1,out: packed split-bf16 [N][128]. W planes: [128 c][256 k] bf16 hi/lo.
// Block = 256 thr = 4 waves; wave computes 16 nodes x 128 cols; no LDS/barriers.
// Safe in-place (out==A1): each wave reads only its own 16 rows, writes them last.
__global__ __launch_bounds__(256) void k_sage_gemm_mfma(
        const unsigned* __restrict__ A0p, const unsigned* __restrict__ A1p,
        const unsigned short* __restrict__ Whi, const unsigned short* __restrict__ Wlo,
        const float* __restrict__ bias, unsigned* __restrict__ outp) {
    int wave = __builtin_amdgcn_readfirstlane(threadIdx.x >> 6);
    int lane = threadIdx.x & 63;
    int n0 = blockIdx.x * 64 + wave * 16;
    if (n0 >= NN) return;                 // whole wave out of range
    int row = lane & 15;                  // A row within tile / D col
    int kb  = lane >> 4;                  // k-block 0..3
    int node = n0 + row;
    int rowc = node < NN ? node : NN - 1; // clamp loads, guard stores

    f32x4 acc[8];
#pragma unroll
    for (int i = 0; i < 8; ++i) acc[i] = (f32x4){0.f, 0.f, 0.f, 0.f};

#pragma unroll
    for (int kc = 0; kc < 8; ++kc) {
        const unsigned* Ap = (kc < 4) ? A0p : A1p;
        int kloc = (kc & 3) * 32 + kb * 8;      // k within the 128-wide source
        int kg   = kc * 32 + kb * 8;            // k within combined 256
        const unsigned* ap = Ap + (size_t)rowc * 128 + kloc;
        uint4 q0 = *(const uint4*)ap;
        uint4 q1 = *(const uint4*)(ap + 4);
        unsigned pk[8] = {q0.x, q0.y, q0.z, q0.w, q1.x, q1.y, q1.z, q1.w};
        bf16x8 ahi, alo;
#pragma unroll
        for (int j = 0; j < 8; ++j) {
            ahi[j] = (short)(pk[j] >> 16);
            alo[j] = (short)(pk[j] & 0xFFFFu);
        }
#pragma unroll
        for (int ct = 0; ct < 8; ++ct) {
            size_t widx = (size_t)(ct * 16 + row) * 256 + kg;
            bf16x8 bhi = *(const bf16x8*)(Whi + widx);
            bf16x8 blo = *(const bf16x8*)(Wlo + widx);
            acc[ct] = __builtin_amdgcn_mfma_f32_16x16x32_bf16(ahi, bhi, acc[ct], 0, 0, 0);
            acc[ct] = __builtin_amdgcn_mfma_f32_16x16x32_bf16(alo, bhi, acc[ct], 0, 0, 0);
            acc[ct] = __builtin_amdgcn_mfma_f32_16x16x32_bf16(ahi, blo, acc[ct], 0, 0, 0);
        }
    }

    // C/D layout (verified): col = lane&15, row = (lane>>4)*4 + reg
    int colb = row;            // output col within tile
    int rbase = kb * 4;        // output row within tile
#pragma unroll
    for (int ct = 0; ct < 8; ++ct) {
        float b = bias[ct * 16 + colb];
#pragma unroll
        for (int r = 0; r < 4; ++r) {
            int n = n0 + rbase + r;
            if (n < NN) {
                float v = fmaxf(acc[ct][r] + b, 0.f);
                outp[(size_t)n * 128 + ct * 16 + colb] = pack_split(v);
            }
        }
    }
}

// ---------------- head ----------------
__global__ __launch_bounds__(256) void k_final(const unsigned* __restrict__ hp,
        const float* __restrict__ Wf, const float* __restrict__ bf,
        float* __restrict__ out) {
    int wave = __builtin_amdgcn_readfirstlane(threadIdx.x >> 6);
    int lane = threadIdx.x & 63;
    int node = blockIdx.x * 4 + wave;
    if (node >= NN) return;
    float2 w = ((const float2*)Wf)[lane];
    uint2 q = ((const uint2*)(hp + (size_t)node * 128))[lane];
    float s = unpack_f(q.x) * w.x + unpack_f(q.y) * w.y;
    for (int o = 32; o > 0; o >>= 1) s += __shfl_down(s, o);
    if (lane == 0) out[node] = s + bf[0];
}

extern "C" void kernel_launch(void* const* d_in, const int* in_sizes, int n_in,
                              void* d_out, int out_size, void* d_ws, size_t ws_size,
                              hipStream_t stream) {
    const float* x   = (const float*)d_in[0];
    const int*   ei  = (const int*)d_in[1];
    const float* Wl0 = (const float*)d_in[2];
    const float* bl0 = (const float*)d_in[3];
    const float* Wr0 = (const float*)d_in[4];
    const float* Wl1 = (const float*)d_in[5];
    const float* bl1 = (const float*)d_in[6];
    const float* Wr1 = (const float*)d_in[7];
    const float* Wl2 = (const float*)d_in[8];
    const float* bl2 = (const float*)d_in[9];
    const float* Wr2 = (const float*)d_in[10];
    const float* Wf  = (const float*)d_in[11];
    const float* bf  = (const float*)d_in[12];
    float* out = (float*)d_out;

    char* p = (char*)d_ws;
    auto alloc = [&](size_t n) { void* r = (void*)p; p += (n + 255) & ~(size_t)255; return r; };
    int*            cnt     = (int*)alloc((size_t)NN * 4);
    int*            cursor  = (int*)alloc((size_t)NN * 4);
    int*            partial = (int*)alloc(256 * 4);
    int*            perm    = (int*)alloc((size_t)NE * 4);
    unsigned*       sbuf    = (unsigned*)alloc((size_t)NN * 128 * 4);  // packed mean
    unsigned*       hp      = (unsigned*)alloc((size_t)NN * 128 * 4);  // packed features
    unsigned short* whi     = (unsigned short*)alloc((size_t)3 * 128 * 256 * 2);
    unsigned short* wlo     = (unsigned short*)alloc((size_t)3 * 128 * 256 * 2);

    dim3 b256(256);
    // CSR build
    k_zero_int<<<dim3((NN + 255) / 256), b256, 0, stream>>>(cnt, NN);
    k_count<<<dim3((NE + 255) / 256), b256, 0, stream>>>(ei, cnt);
    k_chunk_sums<<<dim3(NCH), b256, 0, stream>>>(cnt, partial);
    k_scan_partials<<<dim3(1), b256, 0, stream>>>(partial, NCH);
    k_scan_chunks<<<dim3(NCH), b256, 0, stream>>>(cnt, partial, cursor);
    k_scatter<<<dim3((NE + 255) / 256), b256, 0, stream>>>(ei, cursor, perm);

    // packing
    k_pack_x<<<dim3((NN * 128 / 4 + 255) / 256), b256, 0, stream>>>(x, hp);
    k_pack_w<<<dim3(128, 1), b256, 0, stream>>>(Wl0, Wr0, whi + 0 * 32768, wlo + 0 * 32768);
    k_pack_w<<<dim3(128, 1), b256, 0, stream>>>(Wl1, Wr1, whi + 1 * 32768, wlo + 1 * 32768);
    k_pack_w<<<dim3(128, 1), b256, 0, stream>>>(Wl2, Wr2, whi + 2 * 32768, wlo + 2 * 32768);

    dim3 gAgg((NN + 3) / 4);
    dim3 gGemm((NN + 63) / 64);

    // layer 0
    k_aggregate<<<gAgg, b256, 0, stream>>>(hp, cursor, cnt, perm, sbuf);
    k_sage_gemm_mfma<<<gGemm, b256, 0, stream>>>(sbuf, hp, whi + 0 * 32768, wlo + 0 * 32768, bl0, hp);
    // layer 1 (in place)
    k_aggregate<<<gAgg, b256, 0, stream>>>(hp, cursor, cnt, perm, sbuf);
    k_sage_gemm_mfma<<<gGemm, b256, 0, stream>>>(sbuf, hp, whi + 1 * 32768, wlo + 1 * 32768, bl1, hp);
    // layer 2 (in place)
    k_aggregate<<<gAgg, b256, 0, stream>>>(hp, cursor, cnt, perm, sbuf);
    k_sage_gemm_mfma<<<gGemm, b256, 0, stream>>>(sbuf, hp, whi + 2 * 32768, wlo + 2 * 32768, bl2, hp);
    // head
    k_final<<<gAgg, b256, 0, stream>>>(hp, Wf, bf, out);
}

// Round 5
// 459.152 us; speedup vs baseline: 1.2515x; 1.2515x over previous
//
#include <hip/hip_runtime.h>
#include <hip/hip_bf16.h>

// GraphSage: 3x SAGEConv(mean) + linear head.
// Precision: packed split-bf16 (uint32 = hi<<16|lo, val = f(hi)+f(lo)).
// GEMM: weight-stationary MFMA — each wave owns 32 cols, hoists B hi/lo
// fragments into 128 VGPRs once, grid-strides over 16-node tiles loading
// only A. Triple product A_hi*B_hi + A_lo*B_hi + A_hi*B_lo per K-chunk.
// Layer 2 fuses the linear head (no h3 write; atomicAdd into out=bf).
// CSR build once per call (edge_index int32: [src[0..E), dst[0..E)]).

constexpr int NN = 50000;
constexpr int NE = 800000;
constexpr int NCH = (NN + 255) / 256;
constexpr int NTILE = NN / 16;          // 3125 exact

using bf16x8 = __attribute__((ext_vector_type(8))) short;
using f32x4  = __attribute__((ext_vector_type(4))) float;

__device__ __forceinline__ unsigned short bf16_rne(float f) {
    unsigned u = __float_as_uint(f);
    unsigned r = (u + 0x7FFFu + ((u >> 16) & 1u)) >> 16;
    return (unsigned short)r;
}
__device__ __forceinline__ float bf16_f(unsigned short h) {
    return __uint_as_float(((unsigned)h) << 16);
}
__device__ __forceinline__ unsigned pack_split(float v) {
    unsigned short hi = bf16_rne(v);
    float r = v - bf16_f(hi);
    unsigned short lo = bf16_rne(r);
    return (((unsigned)hi) << 16) | (unsigned)lo;
}
__device__ __forceinline__ float unpack_f(unsigned p) {
    return bf16_f((unsigned short)(p >> 16)) + bf16_f((unsigned short)(p & 0xFFFFu));
}

// ---------------- CSR build ----------------

__global__ void k_zero_int(int* __restrict__ a, int n) {
    int i = blockIdx.x * blockDim.x + threadIdx.x;
    if (i < n) a[i] = 0;
}

__global__ void k_count(const int* __restrict__ ei, int* __restrict__ cnt) {
    int e = blockIdx.x * blockDim.x + threadIdx.x;
    if (e < NE) atomicAdd(&cnt[ei[NE + e]], 1);
}

__global__ void k_chunk_sums(const int* __restrict__ cnt, int* __restrict__ partial) {
    __shared__ int ws[4];
    int i = blockIdx.x * 256 + threadIdx.x;
    int v = (i < NN) ? cnt[i] : 0;
    for (int o = 32; o > 0; o >>= 1) v += __shfl_down(v, o);
    int lane = threadIdx.x & 63, wave = threadIdx.x >> 6;
    if (lane == 0) ws[wave] = v;
    __syncthreads();
    if (threadIdx.x == 0) partial[blockIdx.x] = ws[0] + ws[1] + ws[2] + ws[3];
}

__global__ void k_scan_partials(int* __restrict__ partial, int n) {
    __shared__ int ws[4];
    int t = threadIdx.x;
    int orig = (t < n) ? partial[t] : 0;
    int v = orig;
    int lane = t & 63, wave = t >> 6;
    for (int o = 1; o < 64; o <<= 1) { int u = __shfl_up(v, o); if (lane >= o) v += u; }
    if (lane == 63) ws[wave] = v;
    __syncthreads();
    int off = 0;
    for (int w = 0; w < 4; ++w) if (w < wave) off += ws[w];
    if (t < n) partial[t] = v + off - orig;
}

__global__ void k_scan_chunks(const int* __restrict__ cnt, const int* __restrict__ partial,
                              int* __restrict__ cursor) {
    __shared__ int ws[4];
    int i = blockIdx.x * 256 + threadIdx.x;
    int orig = (i < NN) ? cnt[i] : 0;
    int v = orig;
    int lane = threadIdx.x & 63, wave = threadIdx.x >> 6;
    for (int o = 1; o < 64; o <<= 1) { int u = __shfl_up(v, o); if (lane >= o) v += u; }
    if (lane == 63) ws[wave] = v;
    __syncthreads();
    int off = partial[blockIdx.x];
    for (int w = 0; w < 4; ++w) if (w < wave) off += ws[w];
    if (i < NN) cursor[i] = v - orig + off;
}

__global__ void k_scatter(const int* __restrict__ ei, int* __restrict__ cursor,
                          int* __restrict__ perm) {
    int e = blockIdx.x * blockDim.x + threadIdx.x;
    if (e < NE) {
        int s = ei[e];
        int d = ei[NE + e];
        int pos = atomicAdd(&cursor[d], 1);
        perm[pos] = s;
    }
}

// ---------------- packing ----------------

__global__ void k_pack_x(const float* __restrict__ x, unsigned* __restrict__ xp) {
    int i = blockIdx.x * blockDim.x + threadIdx.x;
    constexpr int TOT = NN * 128 / 4;
    if (i < TOT) {
        float4 v = ((const float4*)x)[i];
        uint4 o;
        o.x = pack_split(v.x); o.y = pack_split(v.y);
        o.z = pack_split(v.z); o.w = pack_split(v.w);
        ((uint4*)xp)[i] = o;
    }
}

// Wl,Wr [128 out][128 in] fp32 -> combined hi/lo bf16 planes [128 c][256 k]
__global__ void k_pack_w(const float* __restrict__ Wl, const float* __restrict__ Wr,
                         unsigned short* __restrict__ whi, unsigned short* __restrict__ wlo) {
    int i = blockIdx.x * blockDim.x + threadIdx.x;
    if (i < 128 * 256) {
        int c = i >> 8;
        int k = i & 255;
        float v = (k < 128) ? Wl[c * 128 + k] : Wr[c * 128 + (k - 128)];
        unsigned short hi = bf16_rne(v);
        whi[i] = hi;
        wlo[i] = bf16_rne(v - bf16_f(hi));
    }
}

__global__ void k_init_out(float* __restrict__ out, const float* __restrict__ bf) {
    int i = blockIdx.x * blockDim.x + threadIdx.x;
    if (i < NN) out[i] = bf[0];
}

// ---------------- aggregate (mean over CSR neighbors) ----------------
// one wave per node; lane l holds cols [2l, 2l+1] (packed uint2)
__global__ __launch_bounds__(256) void k_aggregate(const unsigned* __restrict__ hp,
        const int* __restrict__ cursor, const int* __restrict__ cnt,
        const int* __restrict__ perm, unsigned* __restrict__ outp) {
    int wave = __builtin_amdgcn_readfirstlane(threadIdx.x >> 6);
    int lane = threadIdx.x & 63;
    int node = blockIdx.x * 4 + wave;
    if (node >= NN) return;
    int deg = cnt[node];
    int start = cursor[node] - deg;
    float ax = 0.f, ay = 0.f;
    int j = 0;
    for (; j + 8 <= deg; j += 8) {          // 8 outstanding gathers
        int s[8];
#pragma unroll
        for (int u = 0; u < 8; ++u) s[u] = perm[start + j + u];
        uint2 q[8];
#pragma unroll
        for (int u = 0; u < 8; ++u) q[u] = ((const uint2*)(hp + (size_t)s[u] * 128))[lane];
#pragma unroll
        for (int u = 0; u < 8; ++u) { ax += unpack_f(q[u].x); ay += unpack_f(q[u].y); }
    }
    for (; j + 4 <= deg; j += 4) {
        int s[4];
#pragma unroll
        for (int u = 0; u < 4; ++u) s[u] = perm[start + j + u];
        uint2 q[4];
#pragma unroll
        for (int u = 0; u < 4; ++u) q[u] = ((const uint2*)(hp + (size_t)s[u] * 128))[lane];
#pragma unroll
        for (int u = 0; u < 4; ++u) { ax += unpack_f(q[u].x); ay += unpack_f(q[u].y); }
    }
    for (; j < deg; ++j) {
        int s = perm[start + j];
        uint2 q = ((const uint2*)(hp + (size_t)s * 128))[lane];
        ax += unpack_f(q.x);
        ay += unpack_f(q.y);
    }
    float inv = 1.0f / (float)(deg > 1 ? deg : 1);
    uint2 o;
    o.x = pack_split(ax * inv);
    o.y = pack_split(ay * inv);
    ((uint2*)(outp + (size_t)node * 128))[lane] = o;
}

// ---------------- weight-stationary MFMA GEMM ----------------
// out[n][c] = relu( bias[c] + sum_k [A0|A1][n][k] W[c][k] )
// Wave w owns cols [32w,32w+32): B hi/lo frags hoisted to 128 VGPRs once.
// Grid-stride over 16-node tiles; all 4 waves share the tile's A rows (L1).
// In-place safe: __syncthreads() between tile reads and tile writes.
__global__ __launch_bounds__(256, 2) void k_gemm_ws(
        const unsigned* __restrict__ A0p, const unsigned* __restrict__ A1p,
        const unsigned short* __restrict__ Whi, const unsigned short* __restrict__ Wlo,
        const float* __restrict__ bias, unsigned* __restrict__ outp) {
    int wave = __builtin_amdgcn_readfirstlane(threadIdx.x >> 6);
    int lane = threadIdx.x & 63;
    int row = lane & 15;        // A row in tile / D col in ct-tile
    int kb = lane >> 4;         // k-subblock 0..3
    int ct0 = wave * 2;

    bf16x8 bh[2][8], bl[2][8];
#pragma unroll
    for (int c = 0; c < 2; ++c)
#pragma unroll
        for (int kc = 0; kc < 8; ++kc) {
            size_t widx = (size_t)((ct0 + c) * 16 + row) * 256 + kc * 32 + kb * 8;
            bh[c][kc] = *(const bf16x8*)(Whi + widx);
            bl[c][kc] = *(const bf16x8*)(Wlo + widx);
        }
    float b0 = bias[ct0 * 16 + row];
    float b1 = bias[ct0 * 16 + 16 + row];

    for (int t = blockIdx.x; t < NTILE; t += gridDim.x) {
        int n0 = t * 16;
        const unsigned* a0 = A0p + (size_t)(n0 + row) * 128 + kb * 8;
        const unsigned* a1 = A1p + (size_t)(n0 + row) * 128 + kb * 8;
        f32x4 acc0 = {0.f, 0.f, 0.f, 0.f};
        f32x4 acc1 = {0.f, 0.f, 0.f, 0.f};
#pragma unroll
        for (int kc = 0; kc < 8; ++kc) {
            const unsigned* ap = ((kc < 4) ? a0 : a1) + (kc & 3) * 32;
            uint4 q0 = *(const uint4*)ap;
            uint4 q1 = *(const uint4*)(ap + 4);
            unsigned pk[8] = {q0.x, q0.y, q0.z, q0.w, q1.x, q1.y, q1.z, q1.w};
            bf16x8 ah, al;
#pragma unroll
            for (int j = 0; j < 8; ++j) {
                ah[j] = (short)(pk[j] >> 16);
                al[j] = (short)(pk[j] & 0xFFFFu);
            }
            acc0 = __builtin_amdgcn_mfma_f32_16x16x32_bf16(ah, bh[0][kc], acc0, 0, 0, 0);
            acc0 = __builtin_amdgcn_mfma_f32_16x16x32_bf16(al, bh[0][kc], acc0, 0, 0, 0);
            acc0 = __builtin_amdgcn_mfma_f32_16x16x32_bf16(ah, bl[0][kc], acc0, 0, 0, 0);
            acc1 = __builtin_amdgcn_mfma_f32_16x16x32_bf16(ah, bh[1][kc], acc1, 0, 0, 0);
            acc1 = __builtin_amdgcn_mfma_f32_16x16x32_bf16(al, bh[1][kc], acc1, 0, 0, 0);
            acc1 = __builtin_amdgcn_mfma_f32_16x16x32_bf16(ah, bl[1][kc], acc1, 0, 0, 0);
        }
        __syncthreads();   // all waves' reads of this tile's rows precede writes
        int cb0 = ct0 * 16 + row;
#pragma unroll
        for (int r = 0; r < 4; ++r) {
            int n = n0 + kb * 4 + r;         // D: col=lane&15, row=(lane>>4)*4+reg
            unsigned* orow = outp + (size_t)n * 128;
            orow[cb0]      = pack_split(fmaxf(acc0[r] + b0, 0.f));
            orow[cb0 + 16] = pack_split(fmaxf(acc1[r] + b1, 0.f));
        }
    }
}

// layer-2 variant: head fused — out[n] += sum_c relu(h3[n][c]) * Wf[c]
__global__ __launch_bounds__(256, 2) void k_gemm_head(
        const unsigned* __restrict__ A0p, const unsigned* __restrict__ A1p,
        const unsigned short* __restrict__ Whi, const unsigned short* __restrict__ Wlo,
        const float* __restrict__ bias, const float* __restrict__ Wf,
        float* __restrict__ out) {
    int wave = __builtin_amdgcn_readfirstlane(threadIdx.x >> 6);
    int lane = threadIdx.x & 63;
    int row = lane & 15;
    int kb = lane >> 4;
    int ct0 = wave * 2;

    bf16x8 bh[2][8], bl[2][8];
#pragma unroll
    for (int c = 0; c < 2; ++c)
#pragma unroll
        for (int kc = 0; kc < 8; ++kc) {
            size_t widx = (size_t)((ct0 + c) * 16 + row) * 256 + kc * 32 + kb * 8;
            bh[c][kc] = *(const bf16x8*)(Whi + widx);
            bl[c][kc] = *(const bf16x8*)(Wlo + widx);
        }
    float b0 = bias[ct0 * 16 + row];
    float b1 = bias[ct0 * 16 + 16 + row];
    float w0 = Wf[ct0 * 16 + row];
    float w1 = Wf[ct0 * 16 + 16 + row];

    for (int t = blockIdx.x; t < NTILE; t += gridDim.x) {
        int n0 = t * 16;
        const unsigned* a0 = A0p + (size_t)(n0 + row) * 128 + kb * 8;
        const unsigned* a1 = A1p + (size_t)(n0 + row) * 128 + kb * 8;
        f32x4 acc0 = {0.f, 0.f, 0.f, 0.f};
        f32x4 acc1 = {0.f, 0.f, 0.f, 0.f};
#pragma unroll
        for (int kc = 0; kc < 8; ++kc) {
            const unsigned* ap = ((kc < 4) ? a0 : a1) + (kc & 3) * 32;
            uint4 q0 = *(const uint4*)ap;
            uint4 q1 = *(const uint4*)(ap + 4);
            unsigned pk[8] = {q0.x, q0.y, q0.z, q0.w, q1.x, q1.y, q1.z, q1.w};
            bf16x8 ah, al;
#pragma unroll
            for (int j = 0; j < 8; ++j) {
                ah[j] = (short)(pk[j] >> 16);
                al[j] = (short)(pk[j] & 0xFFFFu);
            }
            acc0 = __builtin_amdgcn_mfma_f32_16x16x32_bf16(ah, bh[0][kc], acc0, 0, 0, 0);
            acc0 = __builtin_amdgcn_mfma_f32_16x16x32_bf16(al, bh[0][kc], acc0, 0, 0, 0);
            acc0 = __builtin_amdgcn_mfma_f32_16x16x32_bf16(ah, bl[0][kc], acc0, 0, 0, 0);
            acc1 = __builtin_amdgcn_mfma_f32_16x16x32_bf16(ah, bh[1][kc], acc1, 0, 0, 0);
            acc1 = __builtin_amdgcn_mfma_f32_16x16x32_bf16(al, bh[1][kc], acc1, 0, 0, 0);
            acc1 = __builtin_amdgcn_mfma_f32_16x16x32_bf16(ah, bl[1][kc], acc1, 0, 0, 0);
        }
        float part[4];
#pragma unroll
        for (int r = 0; r < 4; ++r)
            part[r] = fmaxf(acc0[r] + b0, 0.f) * w0 + fmaxf(acc1[r] + b1, 0.f) * w1;
        // reduce over the 16-lane col group (xor of bits 0..3 stays in group)
#pragma unroll
        for (int o = 1; o < 16; o <<= 1) {
#pragma unroll
            for (int r = 0; r < 4; ++r) part[r] += __shfl_xor(part[r], o);
        }
        if (row == 0) {
#pragma unroll
            for (int r = 0; r < 4; ++r) atomicAdd(&out[n0 + kb * 4 + r], part[r]);
        }
    }
}

extern "C" void kernel_launch(void* const* d_in, const int* in_sizes, int n_in,
                              void* d_out, int out_size, void* d_ws, size_t ws_size,
                              hipStream_t stream) {
    const float* x   = (const float*)d_in[0];
    const int*   ei  = (const int*)d_in[1];
    const float* Wl0 = (const float*)d_in[2];
    const float* bl0 = (const float*)d_in[3];
    const float* Wr0 = (const float*)d_in[4];
    const float* Wl1 = (const float*)d_in[5];
    const float* bl1 = (const float*)d_in[6];
    const float* Wr1 = (const float*)d_in[7];
    const float* Wl2 = (const float*)d_in[8];
    const float* bl2 = (const float*)d_in[9];
    const float* Wr2 = (const float*)d_in[10];
    const float* Wf  = (const float*)d_in[11];
    const float* bf  = (const float*)d_in[12];
    float* out = (float*)d_out;

    char* p = (char*)d_ws;
    auto alloc = [&](size_t n) { void* r = (void*)p; p += (n + 255) & ~(size_t)255; return r; };
    int*            cnt     = (int*)alloc((size_t)NN * 4);
    int*            cursor  = (int*)alloc((size_t)NN * 4);
    int*            partial = (int*)alloc(256 * 4);
    int*            perm    = (int*)alloc((size_t)NE * 4);
    unsigned*       sbuf    = (unsigned*)alloc((size_t)NN * 128 * 4);
    unsigned*       hp      = (unsigned*)alloc((size_t)NN * 128 * 4);
    unsigned short* whi     = (unsigned short*)alloc((size_t)3 * 128 * 256 * 2);
    unsigned short* wlo     = (unsigned short*)alloc((size_t)3 * 128 * 256 * 2);

    dim3 b256(256);
    // CSR build
    k_zero_int<<<dim3((NN + 255) / 256), b256, 0, stream>>>(cnt, NN);
    k_count<<<dim3((NE + 255) / 256), b256, 0, stream>>>(ei, cnt);
    k_chunk_sums<<<dim3(NCH), b256, 0, stream>>>(cnt, partial);
    k_scan_partials<<<dim3(1), b256, 0, stream>>>(partial, NCH);
    k_scan_chunks<<<dim3(NCH), b256, 0, stream>>>(cnt, partial, cursor);
    k_scatter<<<dim3((NE + 255) / 256), b256, 0, stream>>>(ei, cursor, perm);

    // packing + out init
    k_pack_x<<<dim3((NN * 128 / 4 + 255) / 256), b256, 0, stream>>>(x, hp);
    k_pack_w<<<dim3(128), b256, 0, stream>>>(Wl0, Wr0, whi + 0 * 32768, wlo + 0 * 32768);
    k_pack_w<<<dim3(128), b256, 0, stream>>>(Wl1, Wr1, whi + 1 * 32768, wlo + 1 * 32768);
    k_pack_w<<<dim3(128), b256, 0, stream>>>(Wl2, Wr2, whi + 2 * 32768, wlo + 2 * 32768);
    k_init_out<<<dim3((NN + 255) / 256), b256, 0, stream>>>(out, bf);

    dim3 gAgg((NN + 3) / 4);
    dim3 gGemm(512);   // 2 blocks/CU; grid-stride over 3125 tiles

    // layer 0
    k_aggregate<<<gAgg, b256, 0, stream>>>(hp, cursor, cnt, perm, sbuf);
    k_gemm_ws<<<gGemm, b256, 0, stream>>>(sbuf, hp, whi + 0 * 32768, wlo + 0 * 32768, bl0, hp);
    // layer 1 (in place)
    k_aggregate<<<gAgg, b256, 0, stream>>>(hp, cursor, cnt, perm, sbuf);
    k_gemm_ws<<<gGemm, b256, 0, stream>>>(sbuf, hp, whi + 1 * 32768, wlo + 1 * 32768, bl1, hp);
    // layer 2 + fused head
    k_aggregate<<<gAgg, b256, 0, stream>>>(hp, cursor, cnt, perm, sbuf);
    k_gemm_head<<<gGemm, b256, 0, stream>>>(sbuf, hp, whi + 2 * 32768, wlo + 2 * 32768, bl2, Wf, out);
}